// Round 5
// baseline (486.311 us; speedup 1.0000x reference)
//
#include <hip/hip_runtime.h>
#include <hip/hip_bf16.h>

typedef __hip_bfloat16 bf16;
typedef unsigned int uint32;
typedef __attribute__((ext_vector_type(8))) short s8v;   // 8 bf16 (16B)
typedef __attribute__((ext_vector_type(4))) short s4v;   // 4 bf16 (8B)
typedef __attribute__((ext_vector_type(8))) short bf8v;  // MFMA A/B frag
typedef __attribute__((ext_vector_type(4))) float f4v;   // MFMA accumulator

#define CAP 64          // bucket capacity per destination row (deg ~ Poisson(16); P(>64) ~ 1e-20)
#define CAPSH 6

__device__ __forceinline__ float waveReduce(float v) {
#pragma unroll
    for (int o = 32; o > 0; o >>= 1) v += __shfl_xor(v, o, 64);
    return v;
}

__device__ __forceinline__ short f2bf(float x) {
    __hip_bfloat16 h = __float2bfloat16(x);
    return *reinterpret_cast<short*>(&h);
}
__device__ __forceinline__ float bf2f(short s) {
    return __uint_as_float(((uint32)(unsigned short)s) << 16);
}
__device__ __forceinline__ uint32 pack2(float x, float y) {
    return (uint32)(unsigned short)f2bf(x) | (((uint32)(unsigned short)f2bf(y)) << 16);
}
__device__ __forceinline__ float blo(uint32 d) { return __uint_as_float(d << 16); }
__device__ __forceinline__ float bhi(uint32 d) { return __uint_as_float(d & 0xffff0000u); }
// fast ELU: expm1f library call -> native v_exp_f32 path (error << bf16 rounding)
__device__ __forceinline__ float felu(float x) { return x > 0.f ? x : __expf(x) - 1.f; }

// ------- batched weight transpose + cursor init + attsum clear (one launch) -------
struct WJobs {
    const float* src[5];
    short* dst[5];
    int K[5], N[5], KP[5], total[5];
    int* cursor;
    float* attsum;
    int N2;
};
__global__ void wtrans_all(WJobs jb) {
    int j = blockIdx.y;
    int i = blockIdx.x * blockDim.x + threadIdx.x;
    if (j == 5) {   // aux slice: bucket cursor init + attsum clear
        if (i < jb.N2) jb.cursor[i] = i << CAPSH;
        if (i < 2) jb.attsum[i] = 0.f;
        return;
    }
    if (i >= jb.total[j]) return;
    int KP = jb.KP[j];
    int n = i / KP, k = i - n * KP;
    jb.dst[j][i] = f2bf(k < jb.K[j] ? jb.src[j][(size_t)k * jb.N[j] + n] : 0.f);
}

// ---------------- universal MFMA GEMM (2-job block-range dispatch + optional scatter tail) ----------------
struct GJob {
    const void* A;
    const short* Wt;
    const float* av;
    void* C;
    float* fs;
    float* fd;
    int M;
};
struct SJob {
    const int* rowA; const int* colA;
    const int* rowB; const int* colB;
    int* cursor; int* ecol;
    int E; int NTW; int nbg;
};

template <typename AT, int K, int KPAD, int N, int CSTORE, bool DO_F, bool DO_ATT, bool DO_SCAT>
__global__ __launch_bounds__(256) void mfma_gemm(GJob j0, GJob j1, int nb0,
                                                 float* __restrict__ attsum, int bnd, SJob sj) {
    constexpr int NT = N / 16;
    constexpr int NP = KPAD / 64;
    int t = threadIdx.x;

    if constexpr (DO_SCAT) {   // scatter tail: fills idle memory pipe of the GEMM blocks
        if ((int)blockIdx.x >= sj.nbg) {
            int i = ((int)blockIdx.x - sj.nbg) * 256 + t;
            if (i < sj.E) {
                int r = sj.rowA[i];
                int p0 = atomicAdd(&sj.cursor[r], 1);
                if (p0 < (r << CAPSH) + CAP) sj.ecol[p0] = sj.colA[i];
            } else if (i < 2 * sj.E) {
                int r = sj.NTW + sj.rowB[i - sj.E];
                int p0 = atomicAdd(&sj.cursor[r], 1);
                if (p0 < (r << CAPSH) + CAP) sj.ecol[p0] = sj.colB[i - sj.E];
            }
            return;
        }
    }

    __shared__ short As[64 * 72];
    __shared__ short Ws[N * 72];
    __shared__ float red[8];
    int lane = t & 63;
    int wid = t >> 6;
    int col = lane & 15;
    int quad = lane >> 4;

    int bid = blockIdx.x;
    bool sec = bid >= nb0;
    GJob J = sec ? j1 : j0;
    const AT* A = (const AT*)J.A;
    const short* Wt = J.Wt;
    const float* av = J.av;
    int M = J.M;
    int row0 = (sec ? bid - nb0 : bid) * 64;

    f4v acc[NT];
#pragma unroll
    for (int i = 0; i < NT; ++i) { f4v z = {0.f, 0.f, 0.f, 0.f}; acc[i] = z; }

    // register staging buffers (unused ones are DCE'd per instantiation)
    float4 ra[4];
    s8v rsa[2];
    s8v rb[NT / 2];

    auto issue = [&](int p) {   // issue global loads for phase p into registers
        int k0 = p * 64;
        if constexpr (sizeof(AT) == 4) {
            const float4* A4 = (const float4*)A;
            int f = t & 15, r0 = t >> 4;
#pragma unroll
            for (int r = 0; r < 4; ++r) {
                int gr = row0 + r0 + 16 * r;
                int f4i = (k0 >> 2) + f;
                float4 v = {0.f, 0.f, 0.f, 0.f};
                if (gr < M && f4i < K / 4) v = A4[(size_t)gr * (K / 4) + f4i];
                ra[r] = v;
            }
        } else {
            int c8 = t & 7, r0 = t >> 3;
#pragma unroll
            for (int r = 0; r < 2; ++r) {
                int gr = row0 + r0 + 32 * r;
                s8v v = {0, 0, 0, 0, 0, 0, 0, 0};
                if (gr < M) v = *(const s8v*)&A[(size_t)gr * K + k0 + c8 * 8];
                rsa[r] = v;
            }
        }
        {
            int c8 = t & 7, r0 = t >> 3;
#pragma unroll
            for (int r = 0; r < NT / 2; ++r)
                rb[r] = *(const s8v*)&Wt[(size_t)(r0 + 32 * r) * KPAD + k0 + c8 * 8];
        }
    };
    auto commit = [&]() {   // registers -> LDS (implicit vmcnt wait lands here)
        if constexpr (sizeof(AT) == 4) {
            int f = t & 15, r0 = t >> 4;
#pragma unroll
            for (int r = 0; r < 4; ++r) {
                float4 v = ra[r];
                s4v sv = {f2bf(v.x), f2bf(v.y), f2bf(v.z), f2bf(v.w)};
                *(s4v*)&As[(r0 + 16 * r) * 72 + f * 4] = sv;
            }
        } else {
            int c8 = t & 7, r0 = t >> 3;
#pragma unroll
            for (int r = 0; r < 2; ++r) *(s8v*)&As[(r0 + 32 * r) * 72 + c8 * 8] = rsa[r];
        }
        int c8 = t & 7, r0 = t >> 3;
#pragma unroll
        for (int r = 0; r < NT / 2; ++r) *(s8v*)&Ws[(r0 + 32 * r) * 72 + c8 * 8] = rb[r];
    };

    issue(0);
    for (int p = 0; p < NP; ++p) {
        __syncthreads();            // previous phase's LDS reads complete
        commit();
        __syncthreads();
        if (p + 1 < NP) issue(p + 1);   // overlap next-phase HBM latency with compute
#pragma unroll
        for (int c2 = 0; c2 < 2; ++c2) {
            int ko = c2 * 32 + quad * 8;
            bf8v af = *(const bf8v*)&As[(wid * 16 + col) * 72 + ko];
#pragma unroll
            for (int nt = 0; nt < NT; ++nt) {
                bf8v bf = *(const bf8v*)&Ws[(nt * 16 + col) * 72 + ko];
                acc[nt] = __builtin_amdgcn_mfma_f32_16x16x32_bf16(af, bf, acc[nt], 0, 0, 0);
            }
        }
    }

    int mbase = row0 + wid * 16;
    if constexpr (CSTORE == 1) {
        float* C = (float*)J.C;
#pragma unroll
        for (int nt = 0; nt < NT; ++nt)
#pragma unroll
            for (int r = 0; r < 4; ++r) {
                int gr = mbase + quad * 4 + r;
                if (gr < M) C[(size_t)gr * N + nt * 16 + col] = acc[nt][r];
            }
    } else if constexpr (CSTORE == 2) {
        short* C = (short*)J.C;
#pragma unroll
        for (int nt = 0; nt < NT; ++nt)
#pragma unroll
            for (int r = 0; r < 4; ++r) {
                int gr = mbase + quad * 4 + r;
                if (gr < M) C[(size_t)gr * N + nt * 16 + col] = f2bf(acc[nt][r]);
            }
    }
    if constexpr (DO_F) {
        if (av) {   // runtime guard: job may not need the f_src/f_dst epilogue
            float* fs = J.fs;
            float* fd = J.fd;
            float a0[NT], a1[NT];
#pragma unroll
            for (int nt = 0; nt < NT; ++nt) {
                a0[nt] = av[nt * 16 + col];
                a1[nt] = av[N + nt * 16 + col];
            }
#pragma unroll
            for (int r = 0; r < 4; ++r) {
                float p0 = 0.f, p1 = 0.f;
#pragma unroll
                for (int nt = 0; nt < NT; ++nt) {
                    p0 += acc[nt][r] * a0[nt];
                    p1 += acc[nt][r] * a1[nt];
                }
#pragma unroll
                for (int o = 8; o > 0; o >>= 1) {
                    p0 += __shfl_xor(p0, o, 64);
                    p1 += __shfl_xor(p1, o, 64);
                }
                int gr = mbase + quad * 4 + r;
                if (col == 0 && gr < M) { fs[gr] = p0; fd[gr] = p1; }
            }
        }
    }
    if constexpr (DO_ATT) {
        float s0 = 0.f, s1 = 0.f;
#pragma unroll
        for (int nt = 0; nt < NT; ++nt) {
            float pj = av[nt * 16 + col];
#pragma unroll
            for (int r = 0; r < 4; ++r) {
                int gr = mbase + quad * 4 + r;
                float v = tanhf(acc[nt][r]) * pj;   // rows >= M have acc==0 -> contribute 0
                if (gr < bnd) s0 += v; else s1 += v;
            }
        }
        s0 = waveReduce(s0);
        s1 = waveReduce(s1);
        if (lane == 0) { red[wid] = s0; red[4 + wid] = s1; }
        __syncthreads();
        if (t == 0) {
            atomicAdd(attsum + 0, red[0] + red[1] + red[2] + red[3]);
            atomicAdd(attsum + 1, red[4] + red[5] + red[6] + red[7]);
        }
    }
}

// h[i,:] = mean_16 P[idx[i,j],:] (P bf16, row = 32 uint32) -> H bf16; fused fs/fd.
// half-wave per source row, uint32 (2 cols) per lane.
__global__ void gather_h64(const int* __restrict__ idx, const uint32* __restrict__ P,
                           const float* __restrict__ a,
                           short* __restrict__ H, float* __restrict__ fsv, float* __restrict__ fdv,
                           int N) {
    int wv = (blockIdx.x * blockDim.x + threadIdx.x) >> 6;
    int lane = threadIdx.x & 63;
    if (wv >= N) return;
    int hf = lane >> 5, li = lane & 31;
    const int* ip = idx + wv * 16;
    float a0 = 0.f, a1 = 0.f;
#pragma unroll
    for (int t = 0; t < 8; ++t) {
        int ind = ip[2 * t + hf];
        uint32 d = P[(size_t)ind * 32 + li];
        a0 += blo(d);
        a1 += bhi(d);
    }
    a0 += __shfl_xor(a0, 32, 64);
    a1 += __shfl_xor(a1, 32, 64);
    a0 *= 0.0625f;
    a1 *= 0.0625f;
    if (hf == 0) ((uint32*)H)[(size_t)wv * 32 + li] = pack2(a0, a1);
    float cp = hf ? 0.f : (a0 * a[2 * li] + a1 * a[2 * li + 1]);
    float cq = hf ? 0.f : (a0 * a[64 + 2 * li] + a1 * a[64 + 2 * li + 1]);
    float p = waveReduce(cp);
    float q = waveReduce(cq);
    if (lane == 0) { fsv[wv] = p; fdv[wv] = q; }
}

// ---------------- fused edge-weight + bucket aggregation ----------------
// Lane l precomputes (c,e) for bucket slot l once in parallel; the accumulation loop
// broadcasts via shfl (register-speed) and only does the hb row gather.
// agg64f: quarter-wave x uint2 (4 cols/lane), 4 edges per iteration.
__global__ void agg64f_kernel(const int* __restrict__ cursor, const int* __restrict__ ecol,
                              const float* __restrict__ fs, const float* __restrict__ fd,
                              const uint32* __restrict__ hb, uint32* __restrict__ out,
                              int N2, int NTW) {
    int wv = (blockIdx.x * blockDim.x + threadIdx.x) >> 6;
    int lane = threadIdx.x & 63;
    if (wv >= N2) return;
    int s = wv << CAPSH;
    int ne = min(cursor[wv] - s, CAP);
    int coff = wv < NTW ? 0 : NTW;
    float fsr = fs[wv];
    int cl = 0;
    float el = 0.f;
    if (lane < ne) {
        cl = ecol[s + lane];
        float f = fsr + fd[coff + cl];
        el = __expf(-(f >= 0.f ? f : 0.2f * f));
    }
    int qd = lane >> 4, li = lane & 15;
    const uint2* h2 = (const uint2*)hb;   // row = 16 uint2 (64 bf16)
    float a0 = 0.f, a1 = 0.f, a2 = 0.f, a3 = 0.f, den = 0.f;
    for (int kb = 0; kb < ne; kb += 16) {
        int k0 = kb + qd, k1 = kb + 4 + qd, k2 = kb + 8 + qd, k3 = kb + 12 + qd;  // all < 64
        int c0 = __shfl(cl, k0, 64); float e0 = __shfl(el, k0, 64);
        int c1 = __shfl(cl, k1, 64); float e1 = __shfl(el, k1, 64);
        int c2 = __shfl(cl, k2, 64); float e2 = __shfl(el, k2, 64);
        int c3 = __shfl(cl, k3, 64); float e3 = __shfl(el, k3, 64);
        uint2 d0 = h2[(size_t)(coff + c0) * 16 + li];
        uint2 d1 = h2[(size_t)(coff + c1) * 16 + li];
        uint2 d2 = h2[(size_t)(coff + c2) * 16 + li];
        uint2 d3 = h2[(size_t)(coff + c3) * 16 + li];
        a0 += e0 * blo(d0.x) + e1 * blo(d1.x) + e2 * blo(d2.x) + e3 * blo(d3.x);
        a1 += e0 * bhi(d0.x) + e1 * bhi(d1.x) + e2 * bhi(d2.x) + e3 * bhi(d3.x);
        a2 += e0 * blo(d0.y) + e1 * blo(d1.y) + e2 * blo(d2.y) + e3 * blo(d3.y);
        a3 += e0 * bhi(d0.y) + e1 * bhi(d1.y) + e2 * bhi(d2.y) + e3 * bhi(d3.y);
        den += e0 + e1 + e2 + e3;
    }
    a0 += __shfl_xor(a0, 16, 64); a0 += __shfl_xor(a0, 32, 64);
    a1 += __shfl_xor(a1, 16, 64); a1 += __shfl_xor(a1, 32, 64);
    a2 += __shfl_xor(a2, 16, 64); a2 += __shfl_xor(a2, 32, 64);
    a3 += __shfl_xor(a3, 16, 64); a3 += __shfl_xor(a3, 32, 64);
    den += __shfl_xor(den, 16, 64); den += __shfl_xor(den, 32, 64);
    if (lane < 16) {
        float inv = 1.f / (den + 1e-16f);
        float v0 = felu(a0 * inv);
        float v1 = felu(a1 * inv);
        float v2 = felu(a2 * inv);
        float v3 = felu(a3 * inv);
        uint2 o = {pack2(v0, v1), pack2(v2, v3)};
        ((uint2*)out)[(size_t)wv * 16 + li] = o;
    }
}

// agg128f: half-wave x uint2 (4 cols/lane of 128), 8 edges per iteration, 4 loads in flight.
__global__ void agg128f_kernel(const int* __restrict__ cursor, const int* __restrict__ ecol,
                               const float* __restrict__ fs, const float* __restrict__ fd,
                               const uint32* __restrict__ hb, uint32* __restrict__ out,
                               int N2, int NTW) {
    int wv = (blockIdx.x * blockDim.x + threadIdx.x) >> 6;
    int lane = threadIdx.x & 63;
    if (wv >= N2) return;
    int s = wv << CAPSH;
    int ne = min(cursor[wv] - s, CAP);
    int coff = wv < NTW ? 0 : NTW;
    float fsr = fs[wv];
    int cl = 0;
    float el = 0.f;
    if (lane < ne) {
        cl = ecol[s + lane];
        float f = fsr + fd[coff + cl];
        el = __expf(-(f >= 0.f ? f : 0.2f * f));
    }
    int hf = lane >> 5, li = lane & 31;
    const uint2* h2 = (const uint2*)hb;   // row = 32 uint2 (128 bf16)
    float a0 = 0.f, a1 = 0.f, a2 = 0.f, a3 = 0.f, den = 0.f;
    for (int kb = 0; kb < ne; kb += 8) {
        int k0 = kb + hf, k1 = kb + 2 + hf, k2 = kb + 4 + hf, k3 = kb + 6 + hf;  // all < 64
        int c0 = __shfl(cl, k0, 64); float e0 = __shfl(el, k0, 64);
        int c1 = __shfl(cl, k1, 64); float e1 = __shfl(el, k1, 64);
        int c2 = __shfl(cl, k2, 64); float e2 = __shfl(el, k2, 64);
        int c3 = __shfl(cl, k3, 64); float e3 = __shfl(el, k3, 64);
        uint2 d0 = h2[(size_t)(coff + c0) * 32 + li];
        uint2 d1 = h2[(size_t)(coff + c1) * 32 + li];
        uint2 d2 = h2[(size_t)(coff + c2) * 32 + li];
        uint2 d3 = h2[(size_t)(coff + c3) * 32 + li];
        a0 += e0 * blo(d0.x) + e1 * blo(d1.x) + e2 * blo(d2.x) + e3 * blo(d3.x);
        a1 += e0 * bhi(d0.x) + e1 * bhi(d1.x) + e2 * bhi(d2.x) + e3 * bhi(d3.x);
        a2 += e0 * blo(d0.y) + e1 * blo(d1.y) + e2 * blo(d2.y) + e3 * blo(d3.y);
        a3 += e0 * bhi(d0.y) + e1 * bhi(d1.y) + e2 * bhi(d2.y) + e3 * bhi(d3.y);
        den += e0 + e1 + e2 + e3;
    }
    a0 += __shfl_xor(a0, 32, 64);
    a1 += __shfl_xor(a1, 32, 64);
    a2 += __shfl_xor(a2, 32, 64);
    a3 += __shfl_xor(a3, 32, 64);
    den += __shfl_xor(den, 32, 64);
    if (hf == 0) {
        float inv = 1.f / (den + 1e-16f);
        float v0 = felu(a0 * inv);
        float v1 = felu(a1 * inv);
        float v2 = felu(a2 * inv);
        float v3 = felu(a3 * inv);
        uint2 o = {pack2(v0, v1), pack2(v2, v3)};
        ((uint2*)out)[(size_t)wv * 32 + li] = o;
    }
}

// ---------------- output (bf16 X inputs) ----------------
__global__ void final_kernel(const short* __restrict__ twX, const short* __restrict__ tuX,
                             const int* __restrict__ twi, const int* __restrict__ tui,
                             const float* __restrict__ attsum,
                             const float* __restrict__ outW, const float* __restrict__ outb,
                             float* __restrict__ out, int B, float invNtw, float invNuv) {
    int wave = (blockIdx.x * blockDim.x + threadIdx.x) >> 6;
    int lane = threadIdx.x & 63;
    if (wave >= B) return;
    float z0 = attsum[0] * invNtw, z1 = attsum[1] * invNuv;
    float m = fmaxf(z0, z1);
    float e0 = expf(z0 - m), e1 = expf(z1 - m);
    float a0 = e0 / (e0 + e1), a1 = e1 / (e0 + e1);
    int ti = twi[wave], ui = tui[wave];
    float l0 = 0.f, l1 = 0.f;
#pragma unroll
    for (int p = 0; p < 2; ++p) {
        int j = lane + 64 * p;
        float feat = a0 * bf2f(twX[(size_t)ti * 128 + j]) + a1 * bf2f(tuX[(size_t)ui * 128 + j]);
        l0 += feat * outW[j];
        l1 += feat * outW[128 + j];
    }
    l0 = waveReduce(l0);
    l1 = waveReduce(l1);
    if (lane == 0) {
        l0 += outb[0];
        l1 += outb[1];
        float mm = fmaxf(l0, l1);
        float lse = mm + logf(expf(l0 - mm) + expf(l1 - mm));
        out[wave * 2 + 0] = l0 - lse;
        out[wave * 2 + 1] = l1 - lse;
    }
}

extern "C" void kernel_launch(void* const* d_in, const int* in_sizes, int n_in,
                              void* d_out, int out_size, void* d_ws, size_t ws_size,
                              hipStream_t stream) {
    const int* features_index = (const int*)d_in[0];
    const int* tw_edges = (const int*)d_in[1];
    const int* ut_edges = (const int*)d_in[2];
    const int* tw_gidx = (const int*)d_in[3];
    const int* ut_gidx = (const int*)d_in[4];
    const float* word_emb = (const float*)d_in[5];
    const float* user_emb = (const float*)d_in[6];
    const float* tw_W1 = (const float*)d_in[7];
    const float* tw_a1 = (const float*)d_in[8];
    const float* tw_W2 = (const float*)d_in[9];
    const float* tw_a2 = (const float*)d_in[10];
    const float* tu_W1 = (const float*)d_in[11];
    const float* tu_a1 = (const float*)d_in[12];
    const float* tu_W2 = (const float*)d_in[13];
    const float* tu_a2 = (const float*)d_in[14];
    const float* weight_W = (const float*)d_in[15];
    const float* weight_proj = (const float*)d_in[16];
    const float* out_W = (const float*)d_in[17];
    const float* out_b = (const float*)d_in[18];

    const int E = in_sizes[1] / 2;              // 800000
    const int NTW = in_sizes[0] / 16;           // 50000
    const int VOCAB = in_sizes[5] / 300;        // 50000
    const int UV = in_sizes[6] / 300;           // 50000
    const int B = in_sizes[3];                  // 4096
    const int N2 = NTW + UV;

    char* ws = (char*)d_ws;
    size_t off = 0;
    auto carve = [&](size_t bytes) -> void* {
        void* p = ws + off;
        off += (bytes + 255) & ~(size_t)255;
        return p;
    };
    // Pbuf region sized as before (fp32) but now holds bf16 P; aliased by num1 later.
    float* Pbuf = (float*)carve((size_t)VOCAB * 64 * sizeof(float));     // 12.8 MB region
    short* Hb1 = (short*)carve((size_t)N2 * 64 * sizeof(short));         // 12.8 MB (layer-1 h, both graphs)
    short* H2 = (short*)carve((size_t)N2 * 128 * sizeof(short));         // 25.6 MB (layer-2 h, both graphs)
    short* X = (short*)carve((size_t)N2 * 128 * sizeof(short));          // 25.6 MB (final features)
    float* f_s = (float*)carve((size_t)N2 * sizeof(float));
    float* f_d = (float*)carve((size_t)N2 * sizeof(float));
    float* attsum = (float*)carve(256);
    int* cursor = (int*)carve((size_t)N2 * sizeof(int));
    int* ecol = (int*)carve((size_t)N2 * CAP * sizeof(int));             // 25.6 MB buckets
    short* Wt1tw = (short*)carve((size_t)64 * 320 * sizeof(short));
    short* Wt1tu = (short*)carve((size_t)64 * 320 * sizeof(short));
    short* Wt2tw = (short*)carve((size_t)128 * 64 * sizeof(short));
    short* Wt2tu = (short*)carve((size_t)128 * 64 * sizeof(short));
    short* Wta   = (short*)carve((size_t)128 * 128 * sizeof(short));
    // num1 (N2*64 bf16 = 12.8 MB) aliases the Pbuf region: P's last read (gather_h64)
    // precedes the agg64f write on the same stream.
    short* num1 = ((size_t)VOCAB * 64 * sizeof(float) >= (size_t)N2 * 64 * sizeof(short))
                      ? (short*)Pbuf
                      : (short*)carve((size_t)N2 * 64 * sizeof(short));
    (void)ws_size; (void)n_in; (void)out_size;

    // ---- batched weight transposes + cursor init + attsum clear (one launch) ----
    WJobs jb;
    jb.src[0] = tw_W1;    jb.dst[0] = Wt1tw; jb.K[0] = 300; jb.N[0] = 64;  jb.KP[0] = 320; jb.total[0] = 64 * 320;
    jb.src[1] = tu_W1;    jb.dst[1] = Wt1tu; jb.K[1] = 300; jb.N[1] = 64;  jb.KP[1] = 320; jb.total[1] = 64 * 320;
    jb.src[2] = tw_W2;    jb.dst[2] = Wt2tw; jb.K[2] = 64;  jb.N[2] = 128; jb.KP[2] = 64;  jb.total[2] = 128 * 64;
    jb.src[3] = tu_W2;    jb.dst[3] = Wt2tu; jb.K[3] = 64;  jb.N[3] = 128; jb.KP[3] = 64;  jb.total[3] = 128 * 64;
    jb.src[4] = weight_W; jb.dst[4] = Wta;   jb.K[4] = 128; jb.N[4] = 128; jb.KP[4] = 128; jb.total[4] = 128 * 128;
    jb.cursor = cursor;
    jb.attsum = attsum;
    jb.N2 = N2;
    {
        int gx = (64 * 320 + 255) / 256;
        int gc = (N2 + 255) / 256;
        if (gc > gx) gx = gc;
        dim3 g(gx, 6);
        wtrans_all<<<g, 256, 0, stream>>>(jb);
    }

    SJob sempty{nullptr, nullptr, nullptr, nullptr, nullptr, nullptr, 0, 0, 0};

    // ---- layer-1 projections (both branches) + single-pass CSR scatter as grid tail ----
    // job0: word projection -> P (bf16, no fs/fd); job1: user projection -> Hb1[NTW..) + fs/fd
    {
        GJob a{word_emb, Wt1tw, nullptr, Pbuf, nullptr, nullptr, VOCAB};
        GJob b{user_emb, Wt1tu, tu_a1, Hb1 + (size_t)NTW * 64, f_s + NTW, f_d + NTW, UV};
        int nbw = (VOCAB + 63) / 64, nbu = (UV + 63) / 64;
        int nbg = nbw + nbu;
        int nsc = (2 * E + 255) / 256;
        SJob sj{tw_edges, tw_edges + E, ut_edges, ut_edges + E, cursor, ecol, E, NTW, nbg};
        mfma_gemm<float, 300, 320, 64, 2, true, false, true><<<nbg + nsc, 256, 0, stream>>>(
            a, b, nbw, nullptr, 0, sj);
    }
    gather_h64<<<(NTW + 3) / 4, 256, 0, stream>>>(features_index, (const uint32*)Pbuf, tw_a1,
                                                  Hb1, f_s, f_d, NTW);

    agg64f_kernel<<<(N2 + 3) / 4, 256, 0, stream>>>(cursor, ecol, f_s, f_d,
                                                    (const uint32*)Hb1, (uint32*)num1, N2, NTW);

    // ---- layer-2 GEMM: both branches in one dual-job launch ----
    {
        int nbtw = (NTW + 63) / 64, nbtu = (UV + 63) / 64;
        GJob a{num1, Wt2tw, tw_a2, H2, f_s, f_d, NTW};
        GJob b{num1 + (size_t)NTW * 64, Wt2tu, tu_a2, H2 + (size_t)NTW * 128,
               f_s + NTW, f_d + NTW, UV};
        mfma_gemm<short, 64, 64, 128, 2, true, false, false><<<nbtw + nbtu, 256, 0, stream>>>(
            a, b, nbtw, nullptr, 0, sempty);
    }

    agg128f_kernel<<<(N2 + 3) / 4, 256, 0, stream>>>(cursor, ecol, f_s, f_d,
                                                     (const uint32*)H2, (uint32*)X, N2, NTW);

    // ---- fusion attention reduce: one launch over N2 rows, boundary-split atomics ----
    {
        GJob a{X, Wta, weight_proj, nullptr, nullptr, nullptr, N2};
        int nb = (N2 + 63) / 64;
        mfma_gemm<short, 128, 128, 128, 0, false, true, false><<<nb, 256, 0, stream>>>(
            a, a, nb, attsum, NTW, sempty);
    }

    final_kernel<<<(B + 3) / 4, 256, 0, stream>>>(X, X + (size_t)NTW * 128, tw_gidx, ut_gidx,
                                                  attsum, out_W, out_b, (float*)d_out, B,
                                                  1.0f / (float)NTW, 1.0f / (float)UV);
}